// Round 4
// baseline (3007.581 us; speedup 1.0000x reference)
//
#include <hip/hip_runtime.h>
#include <stdint.h>

typedef unsigned short u16;
typedef unsigned int u32;

#define TB 8192
#define NB 64
#define NC 64
#define NH 10
#define NO 2
#define NBT (NB*TB)

// chunked-scan parameters (LIF chains, decay 0.25 -> subcritical)
#define SC_TC 256
#define SC_W  128
#define SC_S  32   // TB / SC_TC

// ---------------- workspace layout ----------------
static constexpr size_t SZ_BIG  = (size_t)NB * NH * TB * 8;   // 41,943,040  (y1 / av / iin reused)
static constexpr size_t SZ_PAT  = (size_t)NB * TB * 2;        // 1,048,576
static constexpr size_t OFF_BIG  = 0;
static constexpr size_t OFF_XPAT = OFF_BIG  + SZ_BIG;
static constexpr size_t OFF_QPAT = OFF_XPAT + SZ_PAT;
static constexpr size_t OFF_KPAT = OFF_QPAT + SZ_PAT;
static constexpr size_t OFF_VPAT = OFF_KPAT + SZ_PAT;
static constexpr size_t OFF_APAT = OFF_VPAT + SZ_PAT;
static constexpr size_t OFF_CPAT = OFF_APAT + SZ_PAT;
static constexpr size_t OFF_ZPAT = OFF_CPAT + SZ_PAT;
static constexpr size_t OFF_ZERO = OFF_ZPAT + SZ_PAT;   // stats0(160) + histx(4096) + hista(4096)
static constexpr size_t OFF_STATS= OFF_ZERO;
static constexpr size_t OFF_HISTX= OFF_STATS + 160;
static constexpr size_t OFF_HISTA= OFF_HISTX + 4096;
static constexpr size_t OFF_A0D0 = OFF_HISTA + 4096;    // 160
static constexpr size_t OFF_YTAB = OFF_A0D0 + 160;      // 4 layers * 1024*10 dbl = 327680
static constexpr size_t OFF_FTAB = OFF_YTAB + 327680;   // 4 layers * 640 dbl    = 20480
static constexpr size_t WS_NEED  = OFF_FTAB + 20480;

// ================= front GEMM + stats =================
__global__ __launch_bounds__(256) void k_front(const float* __restrict__ eeg,
    const float* __restrict__ wf, const float* __restrict__ bf,
    double* __restrict__ y1, double* __restrict__ stats)
{
  __shared__ double wsh[NH*NC];
  __shared__ double rs[NH][4], rq[NH][4];
  for (int i = threadIdx.x; i < NH*NC; i += 256) wsh[i] = (double)wf[i];
  __syncthreads();
  int t = blockIdx.x*256 + threadIdx.x;
  int b = blockIdx.y;
  const float* ep = eeg + (size_t)b*NC*TB + t;
  double acc[NH];
  #pragma unroll
  for (int h = 0; h < NH; ++h) acc[h] = (double)bf[h];
  for (int c = 0; c < NC; ++c) {
    double e = (double)ep[(size_t)c*TB];
    #pragma unroll
    for (int h = 0; h < NH; ++h) acc[h] += wsh[h*NC + c] * e;
  }
  double* yp = y1 + (size_t)b*NH*TB + t;
  #pragma unroll
  for (int h = 0; h < NH; ++h) yp[(size_t)h*TB] = acc[h];
  int lane = threadIdx.x & 63, w = threadIdx.x >> 6;
  #pragma unroll
  for (int h = 0; h < NH; ++h) {
    double s1 = acc[h], s2 = acc[h]*acc[h];
    for (int off = 32; off; off >>= 1) { s1 += __shfl_down(s1, off); s2 += __shfl_down(s2, off); }
    if (lane == 0) { rs[h][w] = s1; rq[h][w] = s2; }
  }
  __syncthreads();
  if (threadIdx.x < NH) {
    int h = threadIdx.x;
    atomicAdd(&stats[h],      rs[h][0]+rs[h][1]+rs[h][2]+rs[h][3]);
    atomicAdd(&stats[NH+h],   rq[h][0]+rq[h][1]+rq[h][2]+rq[h][3]);
  }
}

__global__ void k_stats0(const double* __restrict__ stats, const float* __restrict__ g,
                         const float* __restrict__ be, double* __restrict__ a0d0)
{
  int h = threadIdx.x;
  if (h < NH) {
    double inv = 1.0 / (double)NBT;
    double mean = stats[h] * inv;
    double var  = stats[NH+h] * inv - mean*mean;
    double a = 0.5 * (double)g[h] / sqrt(var + 1e-5);
    a0d0[h] = a;
    a0d0[NH+h] = (double)be[h] - a*mean;
  }
}

// ================= chunked LIF scan over fp64 values =================
template<bool SC>
__global__ __launch_bounds__(64) void k_scan_vals(const double* __restrict__ vals,
    const double* __restrict__ a0d0, u16* __restrict__ outpat)
{
  __shared__ double a[NH], d[NH];
  if constexpr (SC) {
    if (threadIdx.x < NH) { a[threadIdx.x] = a0d0[threadIdx.x]; d[threadIdx.x] = a0d0[NH+threadIdx.x]; }
    __syncthreads();
  }
  int idx = blockIdx.x*64 + threadIdx.x;
  int b = idx >> 5, s = idx & 31;
  int t0 = s * SC_TC;
  int ts = t0 - SC_W; if (ts < 0) ts = 0;
  const double* vp = vals + (size_t)b*NH*TB;
  u16* op = outpat + (size_t)b*TB;
  double u[NH];
  #pragma unroll
  for (int h = 0; h < NH; ++h) u[h] = 0.0;
  for (int t = ts; t < t0 + SC_TC; ++t) {
    u32 pt = 0;
    #pragma unroll
    for (int h = 0; h < NH; ++h) {
      double val = vp[(size_t)h*TB + t];
      if constexpr (SC) val = a[h]*val + d[h];
      double un = 0.25*u[h] + val;
      int sp = (un >= 0.5);
      pt |= (u32)sp << h;
      u[h] = sp ? 0.0 : un;
    }
    if (t >= t0) op[t] = (u16)pt;
  }
}

// ================= pattern histogram =================
__global__ __launch_bounds__(256) void k_hist(const u16* __restrict__ pat, u32* __restrict__ hist)
{
  __shared__ u32 hs[1024];
  for (int i = threadIdx.x; i < 1024; i += 256) hs[i] = 0;
  __syncthreads();
  for (int i = blockIdx.x*256 + threadIdx.x; i < NBT; i += gridDim.x*256)
    atomicAdd(&hs[pat[i]], 1u);
  __syncthreads();
  for (int i = threadIdx.x; i < 1024; i += 256) if (hs[i]) atomicAdd(&hist[i], hs[i]);
}

// ================= full 1024x10 subset-sum table =================
__global__ void k_tab_full(const float* __restrict__ w, double* __restrict__ ytab)
{
  int p = blockIdx.x*256 + threadIdx.x;
  if (p < 1024) {
    #pragma unroll
    for (int h = 0; h < NH; ++h) {
      double s = 0.0;
      #pragma unroll
      for (int j = 0; j < NH; ++j) if ((p >> j) & 1) s += (double)w[h*NH + j];
      ytab[p*NH + h] = s;
    }
  }
}

// ================= bn-fold: stats from histogram -> split tables =================
__global__ __launch_bounds__(1024) void k_fold(const double* __restrict__ ytab,
    const u32* __restrict__ hist, const float* __restrict__ g, const float* __restrict__ be,
    double* __restrict__ ftab)
{
  __shared__ double red[1024];
  __shared__ double ash[NH], dsh[NH], ssum[NH], ssq[NH];
  int tid = threadIdx.x;
  double cnt = (double)hist[tid];
  double yv[NH];
  #pragma unroll
  for (int h = 0; h < NH; ++h) yv[h] = ytab[tid*NH + h];
  for (int h = 0; h < NH; ++h) {
    red[tid] = cnt * yv[h];
    __syncthreads();
    for (int off = 512; off; off >>= 1) { if (tid < off) red[tid] += red[tid+off]; __syncthreads(); }
    if (tid == 0) ssum[h] = red[0];
    __syncthreads();
    red[tid] = cnt * yv[h] * yv[h];
    __syncthreads();
    for (int off = 512; off; off >>= 1) { if (tid < off) red[tid] += red[tid+off]; __syncthreads(); }
    if (tid == 0) ssq[h] = red[0];
    __syncthreads();
  }
  if (tid < NH) {
    double inv = 1.0 / (double)NBT;
    double mean = ssum[tid] * inv;
    double var  = ssq[tid] * inv - mean*mean;
    double a = 0.5 * (double)g[tid] / sqrt(var + 1e-5);
    ash[tid] = a; dsh[tid] = (double)be[tid] - a*mean;
  }
  __syncthreads();
  if (tid < 320) {
    int j = tid / NH, h = tid % NH;
    ftab[j*NH + h]       = ash[h]*ytab[j*NH + h] + dsh[h];       // lo (carries d)
    ftab[320 + j*NH + h] = ash[h]*ytab[(j<<5)*NH + h];           // hi
  }
}

// ================= merged q/k/v chunked LIF scan on patterns =================
__global__ __launch_bounds__(64) void k_scan_qkv(const u16* __restrict__ xpat,
    const double* __restrict__ ftabs, u16* __restrict__ qpat, u16* __restrict__ kpat,
    u16* __restrict__ vpat)
{
  __shared__ double ft[3*640];
  for (int i = threadIdx.x; i < 3*640; i += 64) ft[i] = ftabs[i];
  __syncthreads();
  int idx = blockIdx.x*64 + threadIdx.x;
  int b = idx >> 5, s = idx & 31;
  int t0 = s * SC_TC;
  int ts = t0 - SC_W; if (ts < 0) ts = 0;
  const u16* xp = xpat + (size_t)b*TB;
  double uq[NH], uk[NH], uv[NH];
  #pragma unroll
  for (int h = 0; h < NH; ++h) { uq[h]=0.0; uk[h]=0.0; uv[h]=0.0; }
  for (int t = ts; t < t0 + SC_TC; ++t) {
    int p = xp[t];
    int lo = (p & 31)*NH, hi = 320 + (p >> 5)*NH;
    u32 pq = 0, pk = 0, pv = 0;
    #pragma unroll
    for (int h = 0; h < NH; ++h) {
      double vq = ft[lo+h]       + ft[hi+h];
      double vk = ft[640+lo+h]   + ft[640+hi+h];
      double vv = ft[1280+lo+h]  + ft[1280+hi+h];
      double nq = 0.25*uq[h] + vq; int sq = (nq >= 0.5); pq |= (u32)sq << h; uq[h] = sq ? 0.0 : nq;
      double nk = 0.25*uk[h] + vk; int sk = (nk >= 0.5); pk |= (u32)sk << h; uk[h] = sk ? 0.0 : nk;
      double nv = 0.25*uv[h] + vv; int sv = (nv >= 0.5); pv |= (u32)sv << h; uv[h] = sv ? 0.0 : nv;
    }
    if (t >= t0) {
      qpat[(size_t)b*TB + t] = (u16)pq;
      kpat[(size_t)b*TB + t] = (u16)pk;
      vpat[(size_t)b*TB + t] = (u16)pv;
    }
  }
}

// ================= single-layer (cma) chunked LIF scan on patterns =================
__global__ __launch_bounds__(64) void k_scan_pat1(const u16* __restrict__ inpat,
    const double* __restrict__ ftabl, u16* __restrict__ outpat)
{
  __shared__ double ft[640];
  for (int i = threadIdx.x; i < 640; i += 64) ft[i] = ftabl[i];
  __syncthreads();
  int idx = blockIdx.x*64 + threadIdx.x;
  int b = idx >> 5, s = idx & 31;
  int t0 = s * SC_TC;
  int ts = t0 - SC_W; if (ts < 0) ts = 0;
  const u16* xp = inpat + (size_t)b*TB;
  u16* op = outpat + (size_t)b*TB;
  double u[NH];
  #pragma unroll
  for (int h = 0; h < NH; ++h) u[h] = 0.0;
  for (int t = ts; t < t0 + SC_TC; ++t) {
    int p = xp[t];
    int lo = (p & 31)*NH, hi = 320 + (p >> 5)*NH;
    u32 pt = 0;
    #pragma unroll
    for (int h = 0; h < NH; ++h) {
      double val = ft[lo+h] + ft[hi+h];
      double un = 0.25*u[h] + val;
      int sp = (un >= 0.5);
      pt |= (u32)sp << h;
      u[h] = sp ? 0.0 : un;
    }
    if (t >= t0) op[t] = (u16)pt;
  }
}

// ================= windowed attention (integer-exact) =================
__global__ __launch_bounds__(256) void k_att(const u16* __restrict__ qpat,
    const u16* __restrict__ kpat, const u16* __restrict__ vpat, double* __restrict__ av)
{
  __shared__ double lut[11];
  if (threadIdx.x < 11) lut[threadIdx.x] = (double)threadIdx.x / 10.0;  // correctly rounded n/10
  __syncthreads();
  int t = blockIdx.x*256 + threadIdx.x;
  int b = blockIdx.y;
  const u16* qp = qpat + (size_t)b*TB;
  const u16* kp = kpat + (size_t)b*TB;
  const u16* vp = vpat + (size_t)b*TB;
  u32 q = qp[t];
  double acc[NH];
  #pragma unroll
  for (int h = 0; h < NH; ++h) acc[h] = 0.0;
  #pragma unroll
  for (int w = 0; w < 9; ++w) {
    int tw = t + w - 4;
    u32 kk = 0, vv = 0;
    if (tw >= 0 && tw < TB) { kk = kp[tw]; vv = vp[tw]; }
    double aw = lut[__popc(q & kk)];
    #pragma unroll
    for (int h = 0; h < NH; ++h) acc[h] += ((vv >> h) & 1) ? aw : 0.0;
  }
  double* ap = av + (size_t)b*NH*TB + t;
  #pragma unroll
  for (int h = 0; h < NH; ++h) ap[(size_t)h*TB] = acc[h];
}

// ================= LSNN feed-forward drive (parallel) =================
__global__ __launch_bounds__(256) void k_lsnn_in(const u16* __restrict__ cpat,
    const float* __restrict__ w_in, double* __restrict__ iin)
{
  __shared__ double tl[640];
  for (int e = threadIdx.x; e < 640; e += 256) {
    int half = e / 320, rem = e % 320, j = rem / NH, h = rem % NH;
    int base = half ? 5 : 0;
    double s = 0.0;
    #pragma unroll
    for (int q = 0; q < 5; ++q) if ((j >> q) & 1) s += (double)w_in[h*NH + base + q];
    tl[e] = s;
  }
  __syncthreads();
  int t = blockIdx.x*256 + threadIdx.x;
  int b = blockIdx.y;
  int p = cpat[(size_t)b*TB + t];
  int lo = (p & 31)*NH, hi = 320 + (p >> 5)*NH;
  double* ip = iin + (size_t)b*NH*TB + t;
  #pragma unroll
  for (int h = 0; h < NH; ++h) ip[(size_t)h*TB] = tl[lo+h] + tl[hi+h];
}

// ================= LSNN recurrent scan (sequential, exact) =================
__global__ __launch_bounds__(64) void k_lsnn(const double* __restrict__ iin,
    const float* __restrict__ w_rec, u16* __restrict__ zpat)
{
  int b = blockIdx.x;
  int h = threadIdx.x;
  bool act = (h < NH);
  double wr[NH];
  #pragma unroll
  for (int j = 0; j < NH; ++j) wr[j] = act ? (double)w_rec[h*NH + j] : 0.0;
  const double* ip = iin + (size_t)b*NH*TB + (size_t)(act ? h : 0)*TB;
  u16* zp = zpat + (size_t)b*TB;
  double vm = 0.0, ii = 0.0;
  u32 zprev = 0;
  for (int t = 0; t < TB; ++t) {
    double vdec = vm + 0.1*(ii - vm);
    int sp = act && (vdec >= 0.5);
    unsigned long long mb = __ballot(sp);
    u32 zn = (u32)(mb & 0x3FFull);
    vm = sp ? 0.0 : vdec;
    // recurrent drive uses PREVIOUS z (reference semantics)
    double r01 = ((zprev&1)  ? wr[0] : 0.0) + ((zprev&2)  ? wr[1] : 0.0);
    double r23 = ((zprev&4)  ? wr[2] : 0.0) + ((zprev&8)  ? wr[3] : 0.0);
    double r45 = ((zprev&16) ? wr[4] : 0.0) + ((zprev&32) ? wr[5] : 0.0);
    double r67 = ((zprev&64) ? wr[6] : 0.0) + ((zprev&128)? wr[7] : 0.0);
    double r89 = ((zprev&256)? wr[8] : 0.0) + ((zprev&512)? wr[9] : 0.0);
    double rec = ((r01 + r23) + (r45 + r67)) + r89;
    double xin = act ? ip[t] : 0.0;
    ii = (0.8*ii + xin) + rec;
    zprev = zn;
    if (h == 0) zp[t] = (u16)zn;
  }
}

// ================= closed-form LI readout =================
__global__ __launch_bounds__(256) void k_final(const u16* __restrict__ zpat,
    const float* __restrict__ w_cls, float* __restrict__ out)
{
  __shared__ double red[256];
  __shared__ double A[NH];
  const double L8 = -0.32192809488736235;  // log2(0.8)
  const double L9 = -0.15200309344504997;  // log2(0.9)
  int b = blockIdx.x, tid = threadIdx.x;
  const u16* zp = zpat + (size_t)b*TB;
  double acc[NH];
  #pragma unroll
  for (int h = 0; h < NH; ++h) acc[h] = 0.0;
  for (int t = tid; t < TB; t += 256) {
    int m = TB - 1 - t;
    double c = 5.0 + 4.0*exp2((double)m * L8) - 9.0*exp2((double)m * L9);
    u32 z = zp[t];
    #pragma unroll
    for (int h = 0; h < NH; ++h) if ((z >> h) & 1) acc[h] += c;
  }
  for (int h = 0; h < NH; ++h) {
    red[tid] = acc[h];
    __syncthreads();
    for (int off = 128; off; off >>= 1) { if (tid < off) red[tid] += red[tid+off]; __syncthreads(); }
    if (tid == 0) A[h] = red[0];
    __syncthreads();
  }
  if (tid < NO) {
    double s = 0.0;
    #pragma unroll
    for (int h = 0; h < NH; ++h) s += A[h] * (double)w_cls[tid*NH + h];
    out[b*NO + tid] = (float)(s / (double)TB);
  }
}

// ================= launch =================
extern "C" void kernel_launch(void* const* d_in, const int* in_sizes, int n_in,
                              void* d_out, int out_size, void* d_ws, size_t ws_size,
                              hipStream_t stream)
{
  (void)in_sizes; (void)n_in; (void)out_size;
  if (ws_size < WS_NEED) return;  // insufficient scratch -> cannot run

  const float* eeg  = (const float*)d_in[2];
  const float* wfro = (const float*)d_in[4];
  const float* bfro = (const float*)d_in[5];
  const float* gi   = (const float*)d_in[6];
  const float* bi   = (const float*)d_in[7];
  const float* wq   = (const float*)d_in[8];
  const float* gq   = (const float*)d_in[9];
  const float* bq   = (const float*)d_in[10];
  const float* wk   = (const float*)d_in[11];
  const float* gk   = (const float*)d_in[12];
  const float* bk   = (const float*)d_in[13];
  const float* wv   = (const float*)d_in[14];
  const float* gv   = (const float*)d_in[15];
  const float* bv   = (const float*)d_in[16];
  const float* wcma = (const float*)d_in[17];
  const float* gc   = (const float*)d_in[18];
  const float* bc   = (const float*)d_in[19];
  const float* win  = (const float*)d_in[20];
  const float* wrec = (const float*)d_in[21];
  const float* wcls = (const float*)d_in[22];
  float* out = (float*)d_out;

  char* ws = (char*)d_ws;
  double* big   = (double*)(ws + OFF_BIG);    // y1 -> av -> iin (reused)
  u16* xpat = (u16*)(ws + OFF_XPAT);
  u16* qpat = (u16*)(ws + OFF_QPAT);
  u16* kpat = (u16*)(ws + OFF_KPAT);
  u16* vpat = (u16*)(ws + OFF_VPAT);
  u16* apat = (u16*)(ws + OFF_APAT);
  u16* cpat = (u16*)(ws + OFF_CPAT);
  u16* zpat = (u16*)(ws + OFF_ZPAT);
  double* stats = (double*)(ws + OFF_STATS);
  u32* histx = (u32*)(ws + OFF_HISTX);
  u32* hista = (u32*)(ws + OFF_HISTA);
  double* a0d0 = (double*)(ws + OFF_A0D0);
  double* ytab = (double*)(ws + OFF_YTAB);
  double* ftab = (double*)(ws + OFF_FTAB);

  hipMemsetAsync(ws + OFF_ZERO, 0, 160 + 4096 + 4096, stream);

  // front linear + bn stats (fp64), big = y1[b][h][t]
  k_front<<<dim3(TB/256, NB), 256, 0, stream>>>(eeg, wfro, bfro, big, stats);
  k_stats0<<<1, 32, 0, stream>>>(stats, gi, bi, a0d0);
  // x = lif(bn(y1)), packed patterns
  k_scan_vals<true><<<32, 64, 0, stream>>>(big, a0d0, xpat);
  // q/k/v: pattern histogram -> exact bn stats -> folded split tables -> merged scan
  k_hist<<<64, 256, 0, stream>>>(xpat, histx);
  k_tab_full<<<4, 256, 0, stream>>>(wq, ytab);
  k_tab_full<<<4, 256, 0, stream>>>(wk, ytab + 10240);
  k_tab_full<<<4, 256, 0, stream>>>(wv, ytab + 20480);
  k_fold<<<1, 1024, 0, stream>>>(ytab,         histx, gq, bq, ftab);
  k_fold<<<1, 1024, 0, stream>>>(ytab + 10240, histx, gk, bk, ftab + 640);
  k_fold<<<1, 1024, 0, stream>>>(ytab + 20480, histx, gv, bv, ftab + 1280);
  k_scan_qkv<<<32, 64, 0, stream>>>(xpat, ftab, qpat, kpat, vpat);
  // windowed attention (integer-exact), big = av[b][h][t]
  k_att<<<dim3(TB/256, NB), 256, 0, stream>>>(qpat, kpat, vpat, big);
  k_scan_vals<false><<<32, 64, 0, stream>>>(big, nullptr, apat);
  // cma layer
  k_hist<<<64, 256, 0, stream>>>(apat, hista);
  k_tab_full<<<4, 256, 0, stream>>>(wcma, ytab + 30720);
  k_fold<<<1, 1024, 0, stream>>>(ytab + 30720, hista, gc, bc, ftab + 1920);
  k_scan_pat1<<<32, 64, 0, stream>>>(apat, ftab + 1920, cpat);
  // LSNN: parallel feed-forward drive, then exact sequential recurrent scan
  k_lsnn_in<<<dim3(TB/256, NB), 256, 0, stream>>>(cpat, win, big);
  k_lsnn<<<NB, 64, 0, stream>>>(big, wrec, zpat);
  // closed-form leaky-integrator readout
  k_final<<<NB, 256, 0, stream>>>(zpat, wcls, out);
}

// Round 8
// 1958.357 us; speedup vs baseline: 1.5358x; 1.5358x over previous
//
#include <hip/hip_runtime.h>
#include <stdint.h>

typedef unsigned short u16;
typedef unsigned int u32;
typedef unsigned long long u64;

#define TB 8192
#define NB 64
#define NC 64
#define NH 10
#define NO 2
#define NBT (NB*TB)

// chunked-scan parameters (LIF decay 0.25; 0.25^64 ~ 3e-39 << decision margins)
#define SC_TC 128
#define SC_W  64
#define NCH   (TB/SC_TC)   // 64 chunks per batch

// ---------------- workspace layout ----------------
static constexpr size_t SZ_BIG  = (size_t)NB * NH * TB * 8;   // y1 / av, layout [b][t][h]
static constexpr size_t SZ_PAT  = (size_t)NB * TB * 2;
static constexpr size_t OFF_BIG  = 0;
static constexpr size_t OFF_XPAT = OFF_BIG  + SZ_BIG;
static constexpr size_t OFF_QPAT = OFF_XPAT + SZ_PAT;
static constexpr size_t OFF_KPAT = OFF_QPAT + SZ_PAT;
static constexpr size_t OFF_VPAT = OFF_KPAT + SZ_PAT;
static constexpr size_t OFF_APAT = OFF_VPAT + SZ_PAT;
static constexpr size_t OFF_CPAT = OFF_APAT + SZ_PAT;
static constexpr size_t OFF_ZPAT = OFF_CPAT + SZ_PAT;
static constexpr size_t OFF_ZERO = OFF_ZPAT + SZ_PAT;   // stats(160)+histx(4096)+hista(4096)
static constexpr size_t OFF_STATS= OFF_ZERO;
static constexpr size_t OFF_HISTX= OFF_STATS + 160;
static constexpr size_t OFF_HISTA= OFF_HISTX + 4096;
static constexpr size_t OFF_A0D0 = OFF_HISTA + 4096;
static constexpr size_t OFF_YTAB = OFF_A0D0 + 160;      // 4 * 1024*10 dbl
static constexpr size_t OFF_FTAB = OFF_YTAB + 327680;   // 4 * 640 dbl
static constexpr size_t WS_NEED  = OFF_FTAB + 20480;

// ================= front GEMM + stats (writes y1 as [b][t][h]) =================
__global__ __launch_bounds__(256) void k_front(const float* __restrict__ eeg,
    const float* __restrict__ wf, const float* __restrict__ bf,
    double* __restrict__ y1, double* __restrict__ stats)
{
  __shared__ double wsh[NH*NC];
  __shared__ double rs[NH][4], rq[NH][4];
  for (int i = threadIdx.x; i < NH*NC; i += 256) wsh[i] = (double)wf[i];
  __syncthreads();
  int t = blockIdx.x*256 + threadIdx.x;
  int b = blockIdx.y;
  const float* ep = eeg + (size_t)b*NC*TB + t;
  double acc[NH];
  #pragma unroll
  for (int h = 0; h < NH; ++h) acc[h] = (double)bf[h];
  for (int c = 0; c < NC; ++c) {
    double e = (double)ep[(size_t)c*TB];
    #pragma unroll
    for (int h = 0; h < NH; ++h) acc[h] += wsh[h*NC + c] * e;
  }
  double2* yp = (double2*)(y1 + ((size_t)b*TB + t)*NH);
  #pragma unroll
  for (int h = 0; h < 5; ++h) yp[h] = make_double2(acc[2*h], acc[2*h+1]);
  int lane = threadIdx.x & 63, w = threadIdx.x >> 6;
  #pragma unroll
  for (int h = 0; h < NH; ++h) {
    double s1 = acc[h], s2 = acc[h]*acc[h];
    for (int off = 32; off; off >>= 1) { s1 += __shfl_down(s1, off); s2 += __shfl_down(s2, off); }
    if (lane == 0) { rs[h][w] = s1; rq[h][w] = s2; }
  }
  __syncthreads();
  if (threadIdx.x < NH) {
    int h = threadIdx.x;
    atomicAdd(&stats[h],    rs[h][0]+rs[h][1]+rs[h][2]+rs[h][3]);
    atomicAdd(&stats[NH+h], rq[h][0]+rq[h][1]+rq[h][2]+rq[h][3]);
  }
}

__global__ void k_stats0(const double* __restrict__ stats, const float* __restrict__ g,
                         const float* __restrict__ be, double* __restrict__ a0d0)
{
  int h = threadIdx.x;
  if (h < NH) {
    double inv = 1.0 / (double)NBT;
    double mean = stats[h] * inv;
    double var  = stats[NH+h] * inv - mean*mean;
    double a = 0.5 * (double)g[h] / sqrt(var + 1e-5);
    a0d0[h] = a;
    a0d0[NH+h] = (double)be[h] - a*mean;
  }
}

// ================= chunked LIF scan over fp64 values ([b][t][h] layout) =================
template<bool SC>
__global__ __launch_bounds__(64) void k_scan_vals(const double* __restrict__ vals,
    const double* __restrict__ a0d0, u16* __restrict__ outpat)
{
  __shared__ double a[NH], d[NH];
  if constexpr (SC) {
    if (threadIdx.x < NH) { a[threadIdx.x] = a0d0[threadIdx.x]; d[threadIdx.x] = a0d0[NH+threadIdx.x]; }
    __syncthreads();
  }
  int idx = blockIdx.x*64 + threadIdx.x;
  int b = idx >> 6, s = idx & 63;
  int t0 = s * SC_TC;
  int ts = t0 - SC_W; if (ts < 0) ts = 0;
  const double* vp = vals + (size_t)b*TB*NH;
  u16* op = outpat + (size_t)b*TB;
  double u[NH];
  #pragma unroll
  for (int h = 0; h < NH; ++h) u[h] = 0.0;
  for (int t = ts; t < t0 + SC_TC; ++t) {
    const double2* r = (const double2*)(vp + (size_t)t*NH);
    double2 v0 = r[0], v1 = r[1], v2 = r[2], v3 = r[3], v4 = r[4];
    double vv[NH] = {v0.x, v0.y, v1.x, v1.y, v2.x, v2.y, v3.x, v3.y, v4.x, v4.y};
    u32 pt = 0;
    #pragma unroll
    for (int h = 0; h < NH; ++h) {
      double val = vv[h];
      if constexpr (SC) val = a[h]*val + d[h];
      double un = 0.25*u[h] + val;
      int sp = (un >= 0.5);
      pt |= (u32)sp << h;
      u[h] = sp ? 0.0 : un;
    }
    if (t >= t0) op[t] = (u16)pt;
  }
}

// ================= pattern histogram =================
__global__ __launch_bounds__(256) void k_hist(const u16* __restrict__ pat, u32* __restrict__ hist)
{
  __shared__ u32 hs[1024];
  for (int i = threadIdx.x; i < 1024; i += 256) hs[i] = 0;
  __syncthreads();
  for (int i = blockIdx.x*256 + threadIdx.x; i < NBT; i += gridDim.x*256)
    atomicAdd(&hs[pat[i]], 1u);
  __syncthreads();
  for (int i = threadIdx.x; i < 1024; i += 256) if (hs[i]) atomicAdd(&hist[i], hs[i]);
}

// ================= all four 1024x10 subset-sum tables in one launch =================
__global__ void k_tabs(const float* __restrict__ wq, const float* __restrict__ wk,
                       const float* __restrict__ wv, const float* __restrict__ wc,
                       double* __restrict__ ytab)
{
  int L = blockIdx.y;
  const float* w = (L==0) ? wq : (L==1) ? wk : (L==2) ? wv : wc;
  int p = blockIdx.x*256 + threadIdx.x;
  if (p < 1024) {
    #pragma unroll
    for (int h = 0; h < NH; ++h) {
      double s = 0.0;
      #pragma unroll
      for (int j = 0; j < NH; ++j) if ((p >> j) & 1) s += (double)w[h*NH + j];
      ytab[(size_t)L*10240 + p*NH + h] = s;
    }
  }
}

// ================= bn-fold (shared body) =================
__device__ __forceinline__ void fold_body(const double* ytab, const u32* hist,
    const float* g, const float* be, double* ftab)
{
  __shared__ double red[1024];
  __shared__ double ash[NH], dsh[NH], ssum[NH], ssq[NH];
  int tid = threadIdx.x;
  double cnt = (double)hist[tid];
  double yv[NH];
  #pragma unroll
  for (int h = 0; h < NH; ++h) yv[h] = ytab[tid*NH + h];
  for (int h = 0; h < NH; ++h) {
    red[tid] = cnt * yv[h];
    __syncthreads();
    for (int off = 512; off; off >>= 1) { if (tid < off) red[tid] += red[tid+off]; __syncthreads(); }
    if (tid == 0) ssum[h] = red[0];
    __syncthreads();
    red[tid] = cnt * yv[h] * yv[h];
    __syncthreads();
    for (int off = 512; off; off >>= 1) { if (tid < off) red[tid] += red[tid+off]; __syncthreads(); }
    if (tid == 0) ssq[h] = red[0];
    __syncthreads();
  }
  if (tid < NH) {
    double inv = 1.0 / (double)NBT;
    double mean = ssum[tid] * inv;
    double var  = ssq[tid] * inv - mean*mean;
    double a = 0.5 * (double)g[tid] / sqrt(var + 1e-5);
    ash[tid] = a; dsh[tid] = (double)be[tid] - a*mean;
  }
  __syncthreads();
  if (tid < 320) {
    int j = tid / NH, h = tid % NH;
    ftab[j*NH + h]       = ash[h]*ytab[j*NH + h] + dsh[h];   // lo (carries d)
    ftab[320 + j*NH + h] = ash[h]*ytab[(j<<5)*NH + h];       // hi
  }
}

__global__ __launch_bounds__(1024) void k_fold3(const double* __restrict__ ytab,
    const u32* __restrict__ hist, const float* __restrict__ gq, const float* __restrict__ bq,
    const float* __restrict__ gk, const float* __restrict__ bk,
    const float* __restrict__ gv, const float* __restrict__ bv, double* __restrict__ ftab)
{
  int L = blockIdx.x;
  const float* g  = (L==0) ? gq : (L==1) ? gk : gv;
  const float* be = (L==0) ? bq : (L==1) ? bk : bv;
  fold_body(ytab + (size_t)L*10240, hist, g, be, ftab + (size_t)L*640);
}

__global__ __launch_bounds__(1024) void k_fold1(const double* __restrict__ ytab,
    const u32* __restrict__ hist, const float* __restrict__ g, const float* __restrict__ be,
    double* __restrict__ ftab)
{
  fold_body(ytab, hist, g, be, ftab);
}

// ================= merged q/k/v chunked LIF scan on patterns =================
__global__ __launch_bounds__(64) void k_scan_qkv(const u16* __restrict__ xpat,
    const double* __restrict__ ftabs, u16* __restrict__ qpat, u16* __restrict__ kpat,
    u16* __restrict__ vpat)
{
  __shared__ double ft[3*640];
  for (int i = threadIdx.x; i < 3*640; i += 64) ft[i] = ftabs[i];
  __syncthreads();
  int idx = blockIdx.x*64 + threadIdx.x;
  int b = idx >> 6, s = idx & 63;
  int t0 = s * SC_TC;
  int ts = t0 - SC_W; if (ts < 0) ts = 0;
  const u16* xp = xpat + (size_t)b*TB;
  double uq[NH], uk[NH], uv[NH];
  #pragma unroll
  for (int h = 0; h < NH; ++h) { uq[h]=0.0; uk[h]=0.0; uv[h]=0.0; }
  for (int t = ts; t < t0 + SC_TC; ++t) {
    int p = xp[t];
    int lo = (p & 31)*NH, hi = 320 + (p >> 5)*NH;
    u32 pq = 0, pk = 0, pv = 0;
    #pragma unroll
    for (int h = 0; h < NH; ++h) {
      double vq = ft[lo+h]       + ft[hi+h];
      double vk = ft[640+lo+h]   + ft[640+hi+h];
      double vv = ft[1280+lo+h]  + ft[1280+hi+h];
      double nq = 0.25*uq[h] + vq; int sq = (nq >= 0.5); pq |= (u32)sq << h; uq[h] = sq ? 0.0 : nq;
      double nk = 0.25*uk[h] + vk; int sk = (nk >= 0.5); pk |= (u32)sk << h; uk[h] = sk ? 0.0 : nk;
      double nv = 0.25*uv[h] + vv; int sv = (nv >= 0.5); pv |= (u32)sv << h; uv[h] = sv ? 0.0 : nv;
    }
    if (t >= t0) {
      qpat[(size_t)b*TB + t] = (u16)pq;
      kpat[(size_t)b*TB + t] = (u16)pk;
      vpat[(size_t)b*TB + t] = (u16)pv;
    }
  }
}

// ================= single-layer (cma) chunked LIF scan on patterns =================
__global__ __launch_bounds__(64) void k_scan_pat1(const u16* __restrict__ inpat,
    const double* __restrict__ ftabl, u16* __restrict__ outpat)
{
  __shared__ double ft[640];
  for (int i = threadIdx.x; i < 640; i += 64) ft[i] = ftabl[i];
  __syncthreads();
  int idx = blockIdx.x*64 + threadIdx.x;
  int b = idx >> 6, s = idx & 63;
  int t0 = s * SC_TC;
  int ts = t0 - SC_W; if (ts < 0) ts = 0;
  const u16* xp = inpat + (size_t)b*TB;
  u16* op = outpat + (size_t)b*TB;
  double u[NH];
  #pragma unroll
  for (int h = 0; h < NH; ++h) u[h] = 0.0;
  for (int t = ts; t < t0 + SC_TC; ++t) {
    int p = xp[t];
    int lo = (p & 31)*NH, hi = 320 + (p >> 5)*NH;
    u32 pt = 0;
    #pragma unroll
    for (int h = 0; h < NH; ++h) {
      double val = ft[lo+h] + ft[hi+h];
      double un = 0.25*u[h] + val;
      int sp = (un >= 0.5);
      pt |= (u32)sp << h;
      u[h] = sp ? 0.0 : un;
    }
    if (t >= t0) op[t] = (u16)pt;
  }
}

// ================= windowed attention (integer-exact, writes [b][t][h]) =================
__global__ __launch_bounds__(256) void k_att(const u16* __restrict__ qpat,
    const u16* __restrict__ kpat, const u16* __restrict__ vpat, double* __restrict__ av)
{
  __shared__ double lut[11];
  if (threadIdx.x < 11) lut[threadIdx.x] = (double)threadIdx.x / 10.0;  // correctly rounded n/10
  __syncthreads();
  int t = blockIdx.x*256 + threadIdx.x;
  int b = blockIdx.y;
  const u16* qp = qpat + (size_t)b*TB;
  const u16* kp = kpat + (size_t)b*TB;
  const u16* vp = vpat + (size_t)b*TB;
  u32 q = qp[t];
  double acc[NH];
  #pragma unroll
  for (int h = 0; h < NH; ++h) acc[h] = 0.0;
  #pragma unroll
  for (int w = 0; w < 9; ++w) {
    int tw = t + w - 4;
    u32 kk = 0, vv = 0;
    if (tw >= 0 && tw < TB) { kk = kp[tw]; vv = vp[tw]; }
    double aw = lut[__popc(q & kk)];
    #pragma unroll
    for (int h = 0; h < NH; ++h) acc[h] += ((vv >> h) & 1) ? aw : 0.0;
  }
  double2* ap = (double2*)(av + ((size_t)b*TB + t)*NH);
  #pragma unroll
  for (int h = 0; h < 5; ++h) ap[h] = make_double2(acc[2*h], acc[2*h+1]);
}

// ================= LSNN: fused drive + pipelined sequential recurrent scan =================
__global__ __launch_bounds__(64) void k_lsnn2(const u16* __restrict__ cpat,
    const float* __restrict__ w_in, const float* __restrict__ w_rec, u16* __restrict__ zpat)
{
  __shared__ double tl[640];   // w_in split tables [half][j∈0..31][h]
  for (int e = threadIdx.x; e < 640; e += 64) {
    int half = e / 320, rem = e % 320, j = rem / NH, hh = rem % NH;
    int base = half ? 5 : 0;
    double s = 0.0;
    #pragma unroll
    for (int q = 0; q < 5; ++q) if ((j >> q) & 1) s += (double)w_in[hh*NH + base + q];
    tl[e] = s;
  }
  __syncthreads();
  int b = blockIdx.x;
  int h = threadIdx.x;
  bool act = (h < NH);
  int hh = act ? h : 0;
  double wr[NH];
  #pragma unroll
  for (int j = 0; j < NH; ++j) wr[j] = act ? (double)w_rec[h*NH + j] : 0.0;
  const uint4* cp4 = (const uint4*)(cpat + (size_t)b*TB);  // 8 u16 per uint4
  u16* zp = zpat + (size_t)b*TB;

  double vm = 0.0, ii = 0.0;
  u32 zprev = 0;

  auto compute_x = [&](double* x, uint4 pa, uint4 pb) {
    u32 w[8] = {pa.x, pa.y, pa.z, pa.w, pb.x, pb.y, pb.z, pb.w};
    #pragma unroll
    for (int k = 0; k < 16; ++k) {
      int p = (int)((w[k>>1] >> ((k&1)*16)) & 0x3FFu);
      x[k] = tl[(p & 31)*NH + hh] + tl[320 + (p >> 5)*NH + hh];
    }
  };

  auto step16 = [&](double* X, int cidx) {
    u32 zb[8] = {0,0,0,0,0,0,0,0};
    #pragma unroll
    for (int k = 0; k < 16; ++k) {
      double vdec = vm + 0.1*(ii - vm);
      bool sp = act && (vdec >= 0.5);
      u64 mb = __ballot(sp);
      u32 zn = (u32)(mb & 0x3FFull);
      vm = sp ? 0.0 : vdec;
      u32 z = zprev;
      double r01 = ((z&1)  ? wr[0] : 0.0) + ((z&2)  ? wr[1] : 0.0);
      double r23 = ((z&4)  ? wr[2] : 0.0) + ((z&8)  ? wr[3] : 0.0);
      double r45 = ((z&16) ? wr[4] : 0.0) + ((z&32) ? wr[5] : 0.0);
      double r67 = ((z&64) ? wr[6] : 0.0) + ((z&128)? wr[7] : 0.0);
      double r89 = ((z&256)? wr[8] : 0.0) + ((z&512)? wr[9] : 0.0);
      double rec = ((r01 + r23) + (r45 + r67)) + r89;
      ii = (0.8*ii + X[k]) + rec;      // reference order: (i_dec + xin) + rec
      zprev = zn;
      zb[k>>1] |= zn << ((k&1)*16);
    }
    if (h == 0) {
      uint4* zo = (uint4*)(zp + cidx*16);
      zo[0] = make_uint4(zb[0], zb[1], zb[2], zb[3]);
      zo[1] = make_uint4(zb[4], zb[5], zb[6], zb[7]);
    }
  };

  double xA[16], xB[16];
  uint4 pA0 = cp4[0], pA1 = cp4[1];          // patterns chunk 0
  uint4 pB0 = cp4[2], pB1 = cp4[3];          // patterns chunk 1
  compute_x(xA, pA0, pA1);                   // xin chunk 0

  // invariant at loop head: xA = xin(c); (pB0,pB1) = patterns(c+1)
  for (int c = 0; c < 512; c += 2) {
    int cn2 = (c+2 < 512) ? c+2 : 510;
    pA0 = cp4[2*cn2]; pA1 = cp4[2*cn2+1];    // prefetch patterns(c+2)
    compute_x(xB, pB0, pB1);                 // xin(c+1) (LDS reads overlap steps)
    step16(xA, c);
    int cn3 = (c+3 < 512) ? c+3 : 511;
    pB0 = cp4[2*cn3]; pB1 = cp4[2*cn3+1];    // prefetch patterns(c+3)
    compute_x(xA, pA0, pA1);                 // xin(c+2)
    step16(xB, c+1);
  }
}

// ================= closed-form LI readout =================
__global__ __launch_bounds__(256) void k_final(const u16* __restrict__ zpat,
    const float* __restrict__ w_cls, float* __restrict__ out)
{
  __shared__ double red[256];
  __shared__ double A[NH];
  const double L8 = -0.32192809488736235;  // log2(0.8)
  const double L9 = -0.15200309344504997;  // log2(0.9)
  int b = blockIdx.x, tid = threadIdx.x;
  const u16* zp = zpat + (size_t)b*TB;
  double acc[NH];
  #pragma unroll
  for (int h = 0; h < NH; ++h) acc[h] = 0.0;
  for (int t = tid; t < TB; t += 256) {
    int m = TB - 1 - t;
    double c = 5.0 + 4.0*exp2((double)m * L8) - 9.0*exp2((double)m * L9);
    u32 z = zp[t];
    #pragma unroll
    for (int h = 0; h < NH; ++h) if ((z >> h) & 1) acc[h] += c;
  }
  for (int h = 0; h < NH; ++h) {
    red[tid] = acc[h];
    __syncthreads();
    for (int off = 128; off; off >>= 1) { if (tid < off) red[tid] += red[tid+off]; __syncthreads(); }
    if (tid == 0) A[h] = red[0];
    __syncthreads();
  }
  if (tid < NO) {
    double s = 0.0;
    #pragma unroll
    for (int h = 0; h < NH; ++h) s += A[h] * (double)w_cls[tid*NH + h];
    out[b*NO + tid] = (float)(s / (double)TB);
  }
}

// ================= launch =================
extern "C" void kernel_launch(void* const* d_in, const int* in_sizes, int n_in,
                              void* d_out, int out_size, void* d_ws, size_t ws_size,
                              hipStream_t stream)
{
  (void)in_sizes; (void)n_in; (void)out_size;
  if (ws_size < WS_NEED) return;

  const float* eeg  = (const float*)d_in[2];
  const float* wfro = (const float*)d_in[4];
  const float* bfro = (const float*)d_in[5];
  const float* gi   = (const float*)d_in[6];
  const float* bi   = (const float*)d_in[7];
  const float* wq   = (const float*)d_in[8];
  const float* gq   = (const float*)d_in[9];
  const float* bq   = (const float*)d_in[10];
  const float* wk   = (const float*)d_in[11];
  const float* gk   = (const float*)d_in[12];
  const float* bk   = (const float*)d_in[13];
  const float* wv   = (const float*)d_in[14];
  const float* gv   = (const float*)d_in[15];
  const float* bv   = (const float*)d_in[16];
  const float* wcma = (const float*)d_in[17];
  const float* gc   = (const float*)d_in[18];
  const float* bc   = (const float*)d_in[19];
  const float* win  = (const float*)d_in[20];
  const float* wrec = (const float*)d_in[21];
  const float* wcls = (const float*)d_in[22];
  float* out = (float*)d_out;

  char* ws = (char*)d_ws;
  double* big   = (double*)(ws + OFF_BIG);    // y1 then av, layout [b][t][h]
  u16* xpat = (u16*)(ws + OFF_XPAT);
  u16* qpat = (u16*)(ws + OFF_QPAT);
  u16* kpat = (u16*)(ws + OFF_KPAT);
  u16* vpat = (u16*)(ws + OFF_VPAT);
  u16* apat = (u16*)(ws + OFF_APAT);
  u16* cpat = (u16*)(ws + OFF_CPAT);
  u16* zpat = (u16*)(ws + OFF_ZPAT);
  double* stats = (double*)(ws + OFF_STATS);
  u32* histx = (u32*)(ws + OFF_HISTX);
  u32* hista = (u32*)(ws + OFF_HISTA);
  double* a0d0 = (double*)(ws + OFF_A0D0);
  double* ytab = (double*)(ws + OFF_YTAB);
  double* ftab = (double*)(ws + OFF_FTAB);

  hipMemsetAsync(ws + OFF_ZERO, 0, 160 + 4096 + 4096, stream);

  // front linear + bn stats
  k_front<<<dim3(TB/256, NB), 256, 0, stream>>>(eeg, wfro, bfro, big, stats);
  k_stats0<<<1, 32, 0, stream>>>(stats, gi, bi, a0d0);
  // x = lif(bn(y1))
  k_scan_vals<true><<<NB, 64, 0, stream>>>(big, a0d0, xpat);
  // q/k/v tables + folds + merged scan
  k_hist<<<64, 256, 0, stream>>>(xpat, histx);
  k_tabs<<<dim3(4,4), 256, 0, stream>>>(wq, wk, wv, wcma, ytab);
  k_fold3<<<3, 1024, 0, stream>>>(ytab, histx, gq, bq, gk, bk, gv, bv, ftab);
  k_scan_qkv<<<NB, 64, 0, stream>>>(xpat, ftab, qpat, kpat, vpat);
  // windowed attention (integer-exact) + LIF
  k_att<<<dim3(TB/256, NB), 256, 0, stream>>>(qpat, kpat, vpat, big);
  k_scan_vals<false><<<NB, 64, 0, stream>>>(big, nullptr, apat);
  // cma layer
  k_hist<<<64, 256, 0, stream>>>(apat, hista);
  k_fold1<<<1, 1024, 0, stream>>>(ytab + 30720, hista, gc, bc, ftab + 1920);
  k_scan_pat1<<<NB, 64, 0, stream>>>(apat, ftab + 1920, cpat);
  // LSNN (fused drive, software-pipelined)
  k_lsnn2<<<NB, 64, 0, stream>>>(cpat, win, wrec, zpat);
  // closed-form readout
  k_final<<<NB, 256, 0, stream>>>(zpat, wcls, out);
}